// Round 1
// 559.314 us; speedup vs baseline: 1.2564x; 1.2564x over previous
//
#include <hip/hip_runtime.h>
#include <math.h>

// NGRU: only layer 1 of the 2 parallel GRU layers contributes to the output
// (reference returns h_final[-1]); layer 0 is dead compute and is skipped.
//
// Shapes: x (64,48,256,64) f32; Wih/Whh (2,192,64); bih/bhh (2,192).
// rows = B*N = 16384 independent GRU sequences of length T=48, H=64.
//
// Structure: 256 blocks (1/CU) x 512 threads (8 waves). Block owns 64 rows
// for the entire time loop. Lane j = hidden unit j; each wave register-blocks
// 8 rows.
//
// R1 change: weights staged g-major [384][WPAD=68] (natural global layout,
// no transpose) so each thread reads its 6 gate rows as float4
// (ds_read_b128, immediate offsets, zero address VALU) instead of 24 scalar
// ds_read_b32 per f-block. Pad 68 floats/row => lane j's bank-quad is
// (g+q) mod 8 with 64 consecutive g => 8 lanes/quad = data-path minimum,
// conflict-free. x/h tiles stay [64][64], read as same-address wave
// broadcasts (conflict-free).

#define TT 48
#define HH 64
#define GG 192
#define NN 256
#define RPB 64      // rows per block
#define RPW 8       // rows per wave (register-blocked per thread)
#define NTHREADS 512
#define WPAD 68     // padded weight row length (floats)

__device__ __forceinline__ float sigm(float v) {
    return __builtin_amdgcn_rcpf(1.f + __expf(-v));
}
__device__ __forceinline__ float tanh_f(float v) {
    float a = fabsf(v);
    float e = __expf(2.f * a);                     // inf ok: rcp(inf)=0 -> t=1
    float t = 1.f - 2.f * __builtin_amdgcn_rcpf(e + 1.f);
    return v < 0.f ? -t : t;
}

// Keep accumulation order f-ascending, identical to the previous passing
// kernel (bit-identical numerics).
#define FMA4(ACC, W, V)                      \
    ACC = fmaf(W.x, V.x, ACC);               \
    ACC = fmaf(W.y, V.y, ACC);               \
    ACC = fmaf(W.z, V.z, ACC);               \
    ACC = fmaf(W.w, V.w, ACC);

__global__ __launch_bounds__(NTHREADS, 2)
void ngru_fp32_kernel(const float* __restrict__ x,
                      const float* __restrict__ Wih,
                      const float* __restrict__ Whh,
                      const float* __restrict__ bih,
                      const float* __restrict__ bhh,
                      float* __restrict__ out)
{
    extern __shared__ float lds[];
    float* Wl  = lds;                     // [384][WPAD]: rows 0..191 Wih, 192..383 Whh
    float* hsh = lds + 384 * WPAD;        // [64][64] h state
    float* xsh = hsh + RPB * HH;          // [64][64] x_t tile

    const int tid   = threadIdx.x;
    const int j     = tid & 63;           // hidden unit
    const int wv    = tid >> 6;           // wave 0..7
    const int lr0   = wv * RPW;           // local row base of this wave
    const int grow0 = blockIdx.x * RPB;
    const int bb    = grow0 / NN;         // batch index (64 rows never straddle)
    const int n0    = grow0 % NN;

    const float* Wi = Wih + GG * HH;      // layer 1
    const float* Wh = Whh + GG * HH;

    // stage weights g-major with row pad (float4 copies; layout is already
    // g-major in global, so this is a straight padded copy)
    for (int idx = tid; idx < GG * HH / 4; idx += NTHREADS) {
        int g  = idx >> 4;                // gate-row 0..191
        int f4 = idx & 15;                // float4 index within row
        float4 a = ((const float4*)Wi)[idx];
        float4 b = ((const float4*)Wh)[idx];
        *(float4*)(Wl + g * WPAD + f4 * 4)        = a;
        *(float4*)(Wl + (GG + g) * WPAD + f4 * 4) = b;
    }
    for (int idx = tid; idx < RPB * HH; idx += NTHREADS)
        hsh[idx] = 0.f;

    // per-thread weight row bases (all further addressing via imm offsets)
    const float* wb_ir = Wl + (j)             * WPAD;
    const float* wb_iz = Wl + (64 + j)        * WPAD;
    const float* wb_in = Wl + (128 + j)       * WPAD;
    const float* wb_hr = Wl + (GG + j)        * WPAD;
    const float* wb_hz = Wl + (GG + 64 + j)   * WPAD;
    const float* wb_hn = Wl + (GG + 128 + j)  * WPAD;

    // per-thread biases (layer 1); gi and gh keep SEPARATE biases (r*gh_n!)
    const float bi_r = bih[GG + j];
    const float bi_z = bih[GG + 64 + j];
    const float bi_n = bih[GG + 128 + j];
    const float bh_r = bhh[GG + j];
    const float bh_z = bhh[GG + 64 + j];
    const float bh_n = bhh[GG + 128 + j];

    float hreg[RPW];
    #pragma unroll
    for (int r = 0; r < RPW; ++r) hreg[r] = 0.f;

    __syncthreads();

    for (int t = 0; t < TT; ++t) {
        // stage x_t tile: contiguous 4096 floats for this block
        const float4* xsrc =
            (const float4*)(x + ((size_t)(bb * TT + t) * NN + n0) * HH);
        float4* xdst = (float4*)xsh;
        xdst[tid]            = xsrc[tid];
        xdst[tid + NTHREADS] = xsrc[tid + NTHREADS];
        __syncthreads();   // x staged; prev-step h writes visible

        float ai_r[RPW], ai_z[RPW], ai_n[RPW];
        float ah_r[RPW], ah_z[RPW], ah_n[RPW];
        #pragma unroll
        for (int r = 0; r < RPW; ++r) {
            ai_r[r] = bi_r; ai_z[r] = bi_z; ai_n[r] = bi_n;
            ah_r[r] = bh_r; ah_z[r] = bh_z; ah_n[r] = bh_n;
        }

        // 16 f-blocks of 4; per block: 6 b128 weight reads + 16 b128
        // broadcast reads + 192 FMAs. Partial unroll keeps body ~7 KB
        // (I-cache safe) while letting the scheduler hoist loads.
        #pragma unroll 4
        for (int q = 0; q < 16; ++q) {
            const float4 wir = *(const float4*)(wb_ir + q * 4);
            const float4 wiz = *(const float4*)(wb_iz + q * 4);
            const float4 win = *(const float4*)(wb_in + q * 4);
            const float4 whr = *(const float4*)(wb_hr + q * 4);
            const float4 whz = *(const float4*)(wb_hz + q * 4);
            const float4 whn = *(const float4*)(wb_hn + q * 4);
            #pragma unroll
            for (int r = 0; r < RPW; ++r) {
                float4 xq = *(const float4*)(xsh + (lr0 + r) * HH + q * 4);
                float4 hq = *(const float4*)(hsh + (lr0 + r) * HH + q * 4);
                FMA4(ai_r[r], wir, xq);
                FMA4(ai_z[r], wiz, xq);
                FMA4(ai_n[r], win, xq);
                FMA4(ah_r[r], whr, hq);
                FMA4(ah_z[r], whz, hq);
                FMA4(ah_n[r], whn, hq);
            }
        }
        __syncthreads();   // all waves done reading h/x before h overwrite

        #pragma unroll
        for (int r = 0; r < RPW; ++r) {
            float rg = sigm(ai_r[r] + ah_r[r]);
            float zg = sigm(ai_z[r] + ah_z[r]);
            float ng = tanh_f(fmaf(rg, ah_n[r], ai_n[r]));
            float hn = fmaf(zg, hreg[r] - ng, ng);   // (1-z)n + z h
            hreg[r] = hn;
            hsh[(lr0 + r) * HH + j] = hn;
        }
        // next top-of-loop barrier makes h writes visible before reads
    }

    #pragma unroll
    for (int r = 0; r < RPW; ++r)
        out[(size_t)(grow0 + lr0 + r) * HH + j] = hreg[r];
}

extern "C" void kernel_launch(void* const* d_in, const int* in_sizes, int n_in,
                              void* d_out, int out_size, void* d_ws, size_t ws_size,
                              hipStream_t stream) {
    const float* x   = (const float*)d_in[0];
    const float* Wih = (const float*)d_in[1];
    const float* Whh = (const float*)d_in[2];
    const float* bih = (const float*)d_in[3];
    const float* bhh = (const float*)d_in[4];
    float* out = (float*)d_out;

    const int lds_bytes = (384 * WPAD + 2 * RPB * HH) * sizeof(float); // ~134 KB
    (void)hipFuncSetAttribute((const void*)ngru_fp32_kernel,
                        hipFuncAttributeMaxDynamicSharedMemorySize, lds_bytes);

    dim3 grid(16384 / RPB);     // 256 blocks, one per CU
    dim3 block(NTHREADS);
    ngru_fp32_kernel<<<grid, block, lds_bytes, stream>>>(x, Wih, Whh, bih, bhh, out);
}

// Round 2
// 172.063 us; speedup vs baseline: 4.0840x; 3.2506x over previous
//
#include <hip/hip_runtime.h>
#include <math.h>

// NGRU via MFMA. Only layer 1 of the 2 parallel GRU layers contributes
// (reference returns h_final[-1]); layer 0 is skipped.
//
// Shapes: x (64,48,256,64) f32; Wih/Whh (2,192,64); bih/bhh (2,192).
// rows = B*N = 16384 independent GRU sequences, T=48, H=64.
//
// Per block (64 rows, 8 waves): each step computes one logical GEMM
//   C(64x256) = A(64x128) * B(128x256)
// where A = [x_t | h] (bf16 hi/lo split), and B columns are:
//   [0,64):   k<64 -> Wih_r^T,  k>=64 -> Whh_r^T   (gives gi_r+gh_r)
//   [64,128): k<64 -> Wih_z^T,  k>=64 -> Whh_z^T   (gives gi_z+gh_z)
//   [128,192):k<64 -> Wih_n^T,  k>=64 -> 0         (gives gi_n)
//   [192,256):k<64 -> 0,        k>=64 -> Whh_n^T   (gives gh_n)
// B is time-invariant -> built once into REGISTERS (wave w owns cols
// [32w,32w+32): 2 n-tiles x 4 k-tiles x hi/lo = 64 VGPRs).
// Split-bf16: v = hi + lo (each bf16); product = hh + hl + lh (~2^-17 rel).
// MFMA f32_16x16x32_bf16; C/D layout col=lane&15,row=(lane>>4)*4+reg
// (m89-verified); A: row=lane&15,k=(lane>>4)*8+q; B: col=lane&15,same k.

#define TT 48
#define HH 64
#define GG 192
#define NN 256
#define RPB 64
#define RPW 8
#define NTHREADS 512
#define AK 136          // A-plane row stride in bf16 elems (128 + 8 pad)
#define GPAD 260        // gate buffer row stride in floats (256 + 4 pad)

typedef __attribute__((ext_vector_type(8))) short bs8;     // 8 bf16 (4 VGPRs)
typedef __attribute__((ext_vector_type(4))) float f32x4;   // MFMA accum

__device__ __forceinline__ float sigm(float v) {
    return __builtin_amdgcn_rcpf(1.f + __expf(-v));
}
__device__ __forceinline__ float tanh_f(float v) {
    float a = fabsf(v);
    float e = __expf(2.f * a);
    float t = 1.f - 2.f * __builtin_amdgcn_rcpf(e + 1.f);
    return v < 0.f ? -t : t;
}
__device__ __forceinline__ unsigned short f2bf(float f) {   // RNE f32->bf16
    unsigned u = __float_as_uint(f);
    return (unsigned short)((u + 0x7fffu + ((u >> 16) & 1u)) >> 16);
}
__device__ __forceinline__ float bf2f(unsigned short b) {
    return __uint_as_float(((unsigned)b) << 16);
}

__global__ __launch_bounds__(NTHREADS, 2)
void ngru_mfma_kernel(const float* __restrict__ x,
                      const float* __restrict__ Wih,
                      const float* __restrict__ Whh,
                      const float* __restrict__ bih,
                      const float* __restrict__ bhh,
                      float* __restrict__ out)
{
    extern __shared__ __align__(16) char lds_raw[];
    short* Ahi = (short*)lds_raw;                  // [64][AK] bf16-hi of [x|h]
    short* Alo = Ahi + RPB * AK;                   // [64][AK] bf16-lo
    float* Gs  = (float*)(lds_raw + (size_t)2 * RPB * AK * sizeof(short)); // [64][GPAD]

    const int tid  = threadIdx.x;
    const int lane = tid & 63;
    const int wv   = tid >> 6;          // wave 0..7
    const int c0   = lane & 15;         // MFMA col / A row within tile
    const int rq   = lane >> 4;         // quarter-wave 0..3
    const int lr0  = wv * RPW;          // epilogue rows for this wave

    const int grow0 = blockIdx.x * RPB;
    const int bb    = grow0 / NN;
    const int n0    = grow0 % NN;

    const float* Wi = Wih + GG * HH;    // layer 1
    const float* Wh = Whh + GG * HH;

    // ---- build B fragments in registers (once) ----
    // wave w owns C columns [32w, 32w+32); grp = column group (r,z,gin,ghn)
    const int grp = wv >> 1;
    bs8 Bh[2][4], Bl[2][4];
    #pragma unroll
    for (int nt2 = 0; nt2 < 2; ++nt2) {
        const int jc = (wv * 32 + nt2 * 16 + c0) & 63;
        #pragma unroll
        for (int kt = 0; kt < 4; ++kt) {
            const bool isWi = (kt < 2);
            const bool zero = isWi ? (grp == 3) : (grp == 2);
            bs8 h8, l8;
            if (zero) {
                #pragma unroll
                for (int q = 0; q < 8; ++q) { h8[q] = 0; l8[q] = 0; }
            } else {
                const int gbase = isWi ? grp : (grp == 3 ? 2 : grp);
                const float* src = (isWi ? Wi : Wh)
                                 + (gbase * 64 + jc) * HH + (kt & 1) * 32 + rq * 8;
                #pragma unroll
                for (int q = 0; q < 8; ++q) {
                    unsigned short hb = f2bf(src[q]);
                    unsigned short lb = f2bf(src[q] - bf2f(hb));
                    h8[q] = (short)hb; l8[q] = (short)lb;
                }
            }
            Bh[nt2][kt] = h8; Bl[nt2][kt] = l8;
        }
    }

    // ---- biases (layer 1) for epilogue ----
    const float bi_r = bih[GG + lane];
    const float bi_z = bih[GG + 64 + lane];
    const float bi_n = bih[GG + 128 + lane];
    const float bh_r = bhh[GG + lane];
    const float bh_z = bhh[GG + 64 + lane];
    const float bh_n = bhh[GG + 128 + lane];

    // ---- init: zero h-region of A planes, load x_0, hreg=0 ----
    const int xrow = tid >> 3;          // 0..63
    const int xkc  = (tid & 7) * 8;     // 0,8,...,56
    {
        bs8 z;
        #pragma unroll
        for (int q = 0; q < 8; ++q) z[q] = 0;
        *(bs8*)(Ahi + xrow * AK + 64 + xkc) = z;
        *(bs8*)(Alo + xrow * AK + 64 + xkc) = z;

        const float* xsrc = x + ((size_t)(bb * TT + 0) * NN + n0 + xrow) * HH + xkc;
        float4 p0 = *(const float4*)xsrc;
        float4 p1 = *(const float4*)(xsrc + 4);
        float xv[8] = {p0.x,p0.y,p0.z,p0.w,p1.x,p1.y,p1.z,p1.w};
        bs8 h8, l8;
        #pragma unroll
        for (int q = 0; q < 8; ++q) {
            unsigned short hb = f2bf(xv[q]);
            unsigned short lb = f2bf(xv[q] - bf2f(hb));
            h8[q] = (short)hb; l8[q] = (short)lb;
        }
        *(bs8*)(Ahi + xrow * AK + xkc) = h8;
        *(bs8*)(Alo + xrow * AK + xkc) = l8;
    }

    float hreg[RPW];
    #pragma unroll
    for (int r = 0; r < RPW; ++r) hreg[r] = 0.f;

    __syncthreads();   // A ready for t=0

    for (int t = 0; t < TT; ++t) {
        // ===== MFMA phase: C(64x256) = A(64x128)*B, split-bf16 3 products =====
        f32x4 acc[2][4];
        #pragma unroll
        for (int nt2 = 0; nt2 < 2; ++nt2)
            #pragma unroll
            for (int m = 0; m < 4; ++m)
                acc[nt2][m] = (f32x4){0.f, 0.f, 0.f, 0.f};

        #pragma unroll
        for (int m = 0; m < 4; ++m) {
            const short* ab = Ahi + (m * 16 + c0) * AK + rq * 8;
            const short* al = Alo + (m * 16 + c0) * AK + rq * 8;
            bs8 Ah[4], Al4[4];
            #pragma unroll
            for (int kt = 0; kt < 4; ++kt) {
                Ah[kt]  = *(const bs8*)(ab + kt * 32);
                Al4[kt] = *(const bs8*)(al + kt * 32);
            }
            #pragma unroll
            for (int nt2 = 0; nt2 < 2; ++nt2)
                #pragma unroll
                for (int kt = 0; kt < 4; ++kt) {
                    acc[nt2][m] = __builtin_amdgcn_mfma_f32_16x16x32_bf16(
                        Ah[kt], Bh[nt2][kt], acc[nt2][m], 0, 0, 0);
                    acc[nt2][m] = __builtin_amdgcn_mfma_f32_16x16x32_bf16(
                        Ah[kt], Bl[nt2][kt], acc[nt2][m], 0, 0, 0);
                    acc[nt2][m] = __builtin_amdgcn_mfma_f32_16x16x32_bf16(
                        Al4[kt], Bh[nt2][kt], acc[nt2][m], 0, 0, 0);
                }
        }

        // scatter C -> gate buffer
        #pragma unroll
        for (int nt2 = 0; nt2 < 2; ++nt2) {
            const int colb = wv * 32 + nt2 * 16 + c0;
            #pragma unroll
            for (int m = 0; m < 4; ++m)
                #pragma unroll
                for (int r = 0; r < 4; ++r)
                    Gs[(m * 16 + rq * 4 + r) * GPAD + colb] = acc[nt2][m][r];
        }

        __syncthreads();   // Gs ready; all A reads done

        // ===== epilogue: gates, h update, write h (and x_{t+1}) into A =====
        // issue next-step x loads early (hide HBM under gate math)
        float4 p0, p1;
        if (t + 1 < TT) {
            const float* xsrc =
                x + ((size_t)(bb * TT + (t + 1)) * NN + n0 + xrow) * HH + xkc;
            p0 = *(const float4*)xsrc;
            p1 = *(const float4*)(xsrc + 4);
        }

        #pragma unroll
        for (int r = 0; r < RPW; ++r) {
            const int row = lr0 + r;
            const float* g = Gs + row * GPAD;
            float sr  = g[lane]        + bi_r + bh_r;
            float sz  = g[64 + lane]   + bi_z + bh_z;
            float gin = g[128 + lane]  + bi_n;
            float ghn = g[192 + lane]  + bh_n;
            float rg = sigm(sr);
            float zg = sigm(sz);
            float ng = tanh_f(fmaf(rg, ghn, gin));
            float hn = fmaf(zg, hreg[r] - ng, ng);   // (1-z)n + z h
            hreg[r] = hn;
            unsigned short hb = f2bf(hn);
            unsigned short lb = f2bf(hn - bf2f(hb));
            Ahi[row * AK + 64 + lane] = (short)hb;
            Alo[row * AK + 64 + lane] = (short)lb;
        }

        if (t + 1 < TT) {
            float xv[8] = {p0.x,p0.y,p0.z,p0.w,p1.x,p1.y,p1.z,p1.w};
            bs8 h8, l8;
            #pragma unroll
            for (int q = 0; q < 8; ++q) {
                unsigned short hb = f2bf(xv[q]);
                unsigned short lb = f2bf(xv[q] - bf2f(hb));
                h8[q] = (short)hb; l8[q] = (short)lb;
            }
            *(bs8*)(Ahi + xrow * AK + xkc) = h8;
            *(bs8*)(Alo + xrow * AK + xkc) = l8;
        }

        __syncthreads();   // A ready for next step (h + x_{t+1})
    }

    #pragma unroll
    for (int r = 0; r < RPW; ++r)
        out[(size_t)(grow0 + lr0 + r) * HH + lane] = hreg[r];
}

extern "C" void kernel_launch(void* const* d_in, const int* in_sizes, int n_in,
                              void* d_out, int out_size, void* d_ws, size_t ws_size,
                              hipStream_t stream) {
    const float* x   = (const float*)d_in[0];
    const float* Wih = (const float*)d_in[1];
    const float* Whh = (const float*)d_in[2];
    const float* bih = (const float*)d_in[3];
    const float* bhh = (const float*)d_in[4];
    float* out = (float*)d_out;

    const int lds_bytes = 2 * RPB * AK * (int)sizeof(short)
                        + RPB * GPAD * (int)sizeof(float);   // 101,376 B
    (void)hipFuncSetAttribute((const void*)ngru_mfma_kernel,
                        hipFuncAttributeMaxDynamicSharedMemorySize, lds_bytes);

    dim3 grid(16384 / RPB);     // 256 blocks, one per CU
    dim3 block(NTHREADS);
    ngru_mfma_kernel<<<grid, block, lds_bytes, stream>>>(x, Wih, Whh, bih, bhh, out);
}

// Round 3
// 129.307 us; speedup vs baseline: 5.4343x; 1.3306x over previous
//
#include <hip/hip_runtime.h>
#include <math.h>

// NGRU via MFMA, R3. Only layer 1 of the 2 parallel GRU layers contributes
// (reference returns h_final[-1]); layer 0 is skipped.
//
// Shapes: x (64,48,256,64) f32; Wih/Whh (2,192,64); bih/bhh (2,192).
// rows = B*N = 16384 independent GRU sequences, T=48, H=64.
//
// R3 structure: 512 blocks x 256 threads (4 waves), 32 rows/block,
// 2 blocks/CU (two independent barrier domains -> phase overlap).
// Wave nw owns output columns j in [16nw,16nw+16) for ALL FOUR gates:
// four 16x16 C-tiles per m-tile (g=0:r, 1:z, 2:gin, 3:ghn) -> the whole
// gate epilogue is register-local; the Gs gate buffer of R2 is deleted.
// Zero B-tiles (gin k>=64, ghn k<64) are skipped: 12 kt-slots, 72 MFMA/wave.
//
// A = [x_t | h_{t-1}] bf16 hi/lo planes, PING-PONGED: step t reads buf[t&1],
// writes h_t and x_{t+1} into buf[~t&1] -> ONE barrier per step.
// h written as packed dword pairs (shfl_xor(1)); even lanes write hi plane,
// odd lanes lo plane; lo plane staggered +16 dwords so the combined write
// hits all 32 banks 2-way (free). No sub-word LDS writes anywhere.
//
// Split-bf16: v = hi + lo; product = AhBh + AhBl + AlBh (~2^-17 rel), same
// order as R2 -> bit-identical numerics.

#define TT 48
#define HH 64
#define GG 192
#define NN 256
#define RPB 32          // rows per block
#define NTHREADS 256    // 4 waves
#define AK 136          // A row stride in shorts (128 + 8 pad)
#define PLANE 4384      // shorts per plane (32*136 + 32 stagger pad)
#define ABUF (2*PLANE)  // shorts per A buffer (hi+lo)

typedef __attribute__((ext_vector_type(8))) short bs8;     // 8 bf16
typedef __attribute__((ext_vector_type(4))) float f32x4;   // MFMA accum

__device__ __forceinline__ float sigm(float v) {
    return __builtin_amdgcn_rcpf(1.f + __expf(-v));
}
__device__ __forceinline__ float tanh_f(float v) {
    float a = fabsf(v);
    float e = __expf(2.f * a);
    float t = 1.f - 2.f * __builtin_amdgcn_rcpf(e + 1.f);
    return v < 0.f ? -t : t;
}
__device__ __forceinline__ unsigned short f2bf(float f) {   // RNE f32->bf16
    unsigned u = __float_as_uint(f);
    return (unsigned short)((u + 0x7fffu + ((u >> 16) & 1u)) >> 16);
}
__device__ __forceinline__ float bf2f(unsigned short b) {
    return __uint_as_float(((unsigned)b) << 16);
}

__global__ __launch_bounds__(NTHREADS, 2)
void ngru_mfma3(const float* __restrict__ x,
                const float* __restrict__ Wih,
                const float* __restrict__ Whh,
                const float* __restrict__ bih,
                const float* __restrict__ bhh,
                float* __restrict__ out)
{
    extern __shared__ __align__(16) short lds_s[];   // 2 x ABUF shorts

    const int tid  = threadIdx.x;
    const int lane = tid & 63;
    const int nw   = tid >> 6;          // wave 0..3 -> j slice [16nw,16nw+16)
    const int c0   = lane & 15;         // C col within tile / A row within tile
    const int rq   = lane >> 4;         // quarter-wave
    const int j    = nw * 16 + c0;
    const bool odd = (c0 & 1);

    const int grow0 = blockIdx.x * RPB;
    const int bb    = grow0 / NN;
    const int n0    = grow0 % NN;

    const float* Wi = Wih + GG * HH;    // layer 1
    const float* Wh = Whh + GG * HH;

    // ---- B fragments in registers: 12 kt-slots (zero tiles skipped) ----
    // slot: g<2 -> g*4+kt (kt 0..3); g==2 -> 8+kt (kt 0..1, Wi gate-n);
    //        g==3 -> 10+(kt&1) (kt 2..3, Wh gate-n)
    bs8 Bh[12], Bl[12];
    #pragma unroll
    for (int g = 0; g < 4; ++g) {
        const int ktlo = (g == 3) ? 2 : 0;
        const int kthi = (g == 2) ? 2 : 4;
        #pragma unroll
        for (int kt = ktlo; kt < kthi; ++kt) {
            const int slot = (g < 2) ? g * 4 + kt : 8 + (g - 2) * 2 + (kt & 1);
            const bool isWi = (kt < 2);
            const int gbase = (g >= 2) ? 2 : g;
            const float* src = (isWi ? Wi : Wh)
                             + (gbase * 64 + j) * HH + (kt & 1) * 32 + rq * 8;
            bs8 h8, l8;
            #pragma unroll
            for (int q = 0; q < 8; ++q) {
                float v = src[q];
                unsigned short hb = f2bf(v);
                unsigned short lb = f2bf(v - bf2f(hb));
                h8[q] = (short)hb; l8[q] = (short)lb;
            }
            Bh[slot] = h8; Bl[slot] = l8;
        }
    }

    // ---- biases (layer 1), r/z pre-summed; n biases stay separate ----
    const float brz = bih[GG + j]       + bhh[GG + j];
    const float bzz = bih[GG + 64 + j]  + bhh[GG + 64 + j];
    const float bi_n = bih[GG + 128 + j];
    const float bh_n = bhh[GG + 128 + j];

    // ---- init buf0: zero h region, stage x_0 ----
    const int xrow = tid >> 3;          // 0..31
    const int xkc  = (tid & 7) * 8;     // short offset 0..56
    {
        bs8 z = {0,0,0,0,0,0,0,0};
        *(bs8*)(lds_s + xrow * AK + 64 + xkc)         = z;
        *(bs8*)(lds_s + PLANE + xrow * AK + 64 + xkc) = z;

        const float* xsrc = x + ((size_t)(bb * TT) * NN + n0 + xrow) * HH + xkc;
        float4 p0 = *(const float4*)xsrc;
        float4 p1 = *(const float4*)(xsrc + 4);
        float xv[8] = {p0.x,p0.y,p0.z,p0.w,p1.x,p1.y,p1.z,p1.w};
        bs8 h8, l8;
        #pragma unroll
        for (int q = 0; q < 8; ++q) {
            unsigned short hb = f2bf(xv[q]);
            unsigned short lb = f2bf(xv[q] - bf2f(hb));
            h8[q] = (short)hb; l8[q] = (short)lb;
        }
        *(bs8*)(lds_s + xrow * AK + xkc)         = h8;
        *(bs8*)(lds_s + PLANE + xrow * AK + xkc) = l8;
    }

    float hreg[2][4];
    #pragma unroll
    for (int m = 0; m < 2; ++m)
        #pragma unroll
        for (int r = 0; r < 4; ++r) hreg[m][r] = 0.f;

    __syncthreads();   // buf0 ready for t=0

    for (int t = 0; t < TT; ++t) {
        short* cur = lds_s + (t & 1) * ABUF;
        short* nxt = lds_s + ((t & 1) ^ 1) * ABUF;

        // prefetch x_{t+1} early (HBM latency hides under MFMA+epilogue)
        float4 p0, p1;
        if (t + 1 < TT) {
            const float* xsrc =
                x + ((size_t)(bb * TT + t + 1) * NN + n0 + xrow) * HH + xkc;
            p0 = *(const float4*)xsrc;
            p1 = *(const float4*)(xsrc + 4);
        }

        // ===== MFMA: 4 gate-tiles x 2 m-tiles, all gates land in-lane =====
        f32x4 acc[2][4];
        #pragma unroll
        for (int m = 0; m < 2; ++m)
            #pragma unroll
            for (int g = 0; g < 4; ++g)
                acc[m][g] = (f32x4){0.f, 0.f, 0.f, 0.f};

        #pragma unroll
        for (int m = 0; m < 2; ++m) {
            const short* ab = cur + (m * 16 + c0) * AK + rq * 8;
            bs8 Ah_[4], Al_[4];
            #pragma unroll
            for (int kt = 0; kt < 4; ++kt) {
                Ah_[kt] = *(const bs8*)(ab + kt * 32);
                Al_[kt] = *(const bs8*)(ab + PLANE + kt * 32);
            }
            #pragma unroll
            for (int g = 0; g < 4; ++g) {
                #pragma unroll
                for (int kt = 0; kt < 4; ++kt) {
                    if ((g == 2 && kt >= 2) || (g == 3 && kt < 2)) continue;
                    const int slot = (g < 2) ? g * 4 + kt
                                             : 8 + (g - 2) * 2 + (kt & 1);
                    acc[m][g] = __builtin_amdgcn_mfma_f32_16x16x32_bf16(
                        Ah_[kt], Bh[slot], acc[m][g], 0, 0, 0);
                    acc[m][g] = __builtin_amdgcn_mfma_f32_16x16x32_bf16(
                        Ah_[kt], Bl[slot], acc[m][g], 0, 0, 0);
                    acc[m][g] = __builtin_amdgcn_mfma_f32_16x16x32_bf16(
                        Al_[kt], Bh[slot], acc[m][g], 0, 0, 0);
                }
            }
        }

        // ===== epilogue: fully register-local gates; h -> nxt buffer =====
        short* hplane = nxt + (odd ? PLANE : 0);
        #pragma unroll
        for (int m = 0; m < 2; ++m) {
            #pragma unroll
            for (int r = 0; r < 4; ++r) {
                const int row = m * 16 + rq * 4 + r;
                float sr  = acc[m][0][r] + brz;
                float sz  = acc[m][1][r] + bzz;
                float gin = acc[m][2][r] + bi_n;
                float ghn = acc[m][3][r] + bh_n;
                float rg = sigm(sr);
                float zg = sigm(sz);
                float ng = tanh_f(fmaf(rg, ghn, gin));
                float hn = fmaf(zg, hreg[m][r] - ng, ng);   // (1-z)n + z h
                hreg[m][r] = hn;
                if (t + 1 < TT) {
                    unsigned short hb = f2bf(hn);
                    unsigned short lb = f2bf(hn - bf2f(hb));
                    unsigned packed = (unsigned)hb | ((unsigned)lb << 16);
                    unsigned partner = __shfl_xor(packed, 1);
                    // even lane: hi-plane dword {hb(j), hb(j+1)}
                    // odd  lane: lo-plane dword {lb(j-1), lb(j)}
                    unsigned w = odd
                        ? ((partner >> 16) | (packed & 0xffff0000u))
                        : ((packed & 0xffffu) | (partner << 16));
                    *(unsigned*)(hplane + row * AK + 64 + (j & ~1)) = w;
                }
            }
        }

        if (t + 1 < TT) {
            // stage x_{t+1} into nxt
            float xv[8] = {p0.x,p0.y,p0.z,p0.w,p1.x,p1.y,p1.z,p1.w};
            bs8 h8, l8;
            #pragma unroll
            for (int q = 0; q < 8; ++q) {
                unsigned short hb = f2bf(xv[q]);
                unsigned short lb = f2bf(xv[q] - bf2f(hb));
                h8[q] = (short)hb; l8[q] = (short)lb;
            }
            *(bs8*)(nxt + xrow * AK + xkc)         = h8;
            *(bs8*)(nxt + PLANE + xrow * AK + xkc) = l8;
            __syncthreads();   // nxt (h_t + x_{t+1}) ready for step t+1
        }
    }

    #pragma unroll
    for (int m = 0; m < 2; ++m)
        #pragma unroll
        for (int r = 0; r < 4; ++r)
            out[(size_t)(grow0 + m * 16 + rq * 4 + r) * HH + j] = hreg[m][r];
}

extern "C" void kernel_launch(void* const* d_in, const int* in_sizes, int n_in,
                              void* d_out, int out_size, void* d_ws, size_t ws_size,
                              hipStream_t stream) {
    const float* x   = (const float*)d_in[0];
    const float* Wih = (const float*)d_in[1];
    const float* Whh = (const float*)d_in[2];
    const float* bih = (const float*)d_in[3];
    const float* bhh = (const float*)d_in[4];
    float* out = (float*)d_out;

    const int lds_bytes = 2 * ABUF * (int)sizeof(short);   // 35,072 B
    (void)hipFuncSetAttribute((const void*)ngru_mfma3,
                        hipFuncAttributeMaxDynamicSharedMemorySize, lds_bytes);

    dim3 grid(16384 / RPB);     // 512 blocks, 2 per CU
    dim3 block(NTHREADS);
    ngru_mfma3<<<grid, block, lds_bytes, stream>>>(x, Wih, Whh, bih, bhh, out);
}